// Round 9
// baseline (410.355 us; speedup 1.0000x reference)
//
#include <hip/hip_runtime.h>

// ---------- types ----------
typedef __bf16 bf16x8 __attribute__((ext_vector_type(8)));
typedef float  floatx4 __attribute__((ext_vector_type(4)));
typedef unsigned short ushortx8 __attribute__((ext_vector_type(8)));
typedef unsigned short ushortx4 __attribute__((ext_vector_type(4)));
typedef unsigned short ushortx2 __attribute__((ext_vector_type(2)));

__device__ __forceinline__ float bf2f(unsigned short u) {
    return __uint_as_float(((unsigned)u) << 16);
}
__device__ __forceinline__ unsigned short f2bf(float f) {
    unsigned u = __float_as_uint(f);
    return (unsigned short)((u + 0x7FFFu + ((u >> 16) & 1u)) >> 16);
}

// async global->LDS, 16B per lane; lds dest = wave-uniform base + lane*16.
// NOTE (r6): NEVER use the builtin's imm-offset field (NaN — offset applies to
// the LDS side). All offsets in the global ADDRESS; offset arg always 0.
__device__ __forceinline__ void gload_lds16(const unsigned short* g, unsigned short* l) {
    __builtin_amdgcn_global_load_lds(
        (const __attribute__((address_space(1))) void*)g,
        (__attribute__((address_space(3))) void*)l, 16, 0, 0);
}

// ============================================================================
// STAGED (fragment-order) GLOBAL LAYOUT (r7): A/B pre-packed in the exact
// per-(row-tile,K-step) LDS image so GEMM staging reads are 1KB contiguous.
//   chunk(r, k8): tile=r>>7 rt=r&127 g=rt>>4 mrow=rt&15; kti=k>>6 s q from k
//   elem = ((tile*8+kti)<<13) + ((s*8+g)<<9) + ((q*16+mrow)<<3) + (k&7)
// ============================================================================
#define NKT 8   // K=512 -> 8 K-steps of 64

__device__ __forceinline__ size_t staged_chunk(int r, int c /*k>>3*/) {
    int tile = r >> 7, rt = r & 127;
    int g = rt >> 4, mrow = rt & 15;
    int kti = c >> 3, c7 = c & 7;
    int s = c7 >> 2, q = c7 & 3;
    return (((size_t)tile * NKT + kti) << 13) + ((size_t)(s * 8 + g) << 9)
         + ((size_t)((q << 4) | mrow) << 3);
}

// ---------- conversion helpers ----------
__global__ void cvt_f32_bf16_staged_kernel(const float* __restrict__ in,
                                           unsigned short* __restrict__ out,
                                           int nchunk) {
    int i = blockIdx.x * blockDim.x + threadIdx.x;
    if (i >= nchunk) return;
    int r = i >> 6, c = i & 63;
    float4 v0 = ((const float4*)in)[i * 2];
    float4 v1 = ((const float4*)in)[i * 2 + 1];
    ushortx8 o;
    o[0] = f2bf(v0.x); o[1] = f2bf(v0.y); o[2] = f2bf(v0.z); o[3] = f2bf(v0.w);
    o[4] = f2bf(v1.x); o[5] = f2bf(v1.y); o[6] = f2bf(v1.z); o[7] = f2bf(v1.w);
    *(ushortx8*)(out + staged_chunk(r, c)) = o;
}

__global__ void transpose_cvt_staged_kernel(const float* __restrict__ in,
                                            unsigned short* __restrict__ out,
                                            int K, int N) {
    int idx = blockIdx.x * blockDim.x + threadIdx.x;
    if (idx >= K * N) return;
    int k = idx / N, n = idx - k * N;
    out[staged_chunk(n, k >> 3) + (k & 7)] = f2bf(in[idx]);
}

// ============================================================================
// EDGE SLOTS (r9): the linked-list traversal (head->nxt->nxt, + esrc
// indirection) was a strictly DEPENDENT ~200-900cy VMEM chain per node — the
// props are latency-bound, not BW-bound. Replace with per-(mask,dst) slot
// arrays: list[(m*Nn+d)*CAP + slot] = src. Traversal = 1 broadcast deg load +
// deg INDEPENDENT src loads + deg independent row-gathers (pipelineable).
// CAP=32: degree ~ Poisson(1.33), P(>=32) ~ 1e-30; overflow clamped (would
// fail absmax loudly, deterministically, if ever hit).
// ============================================================================
#define CAP 32

__global__ void zero_cnt_kernel(int* __restrict__ cnt, int n) {
    int i = blockIdx.x * blockDim.x + threadIdx.x;
    if (i < n) cnt[i] = 0;
}

__global__ void build_slots_kernel(const int* __restrict__ ei, const int* __restrict__ em,
                                   int E, int Nn,
                                   int* __restrict__ cnt, int* __restrict__ list) {
    int e = blockIdx.x * blockDim.x + threadIdx.x;
    if (e >= E) return;
    int d = ei[E + e];
    int m = em[e];
    int key = m * Nn + d;
    int slot = atomicAdd(&cnt[key], 1);
    if (slot < CAP) list[(size_t)key * CAP + slot] = ei[e];   // store SRC directly
}

// ---------- GEMM: C[M,N] = A@B + bias; A,Bt in STAGED layout; C linear ------
#define BM 128
#define BN 128

__global__ __launch_bounds__(256, 4) void gemm_bt_bias(
    const unsigned short* __restrict__ A,    // staged [tiles][NKT][16KB]
    const unsigned short* __restrict__ Bt,   // staged
    const float* __restrict__ bias,          // N (fp32)
    unsigned short* __restrict__ C,          // M x N  (bf16 bits), linear
    int M, int N, int K)
{
    __shared__ unsigned short Sh[16384];     // 32 KB: As[16][512] + Bs[16][512]
    unsigned short (*As)[512] = (unsigned short(*)[512])Sh;
    unsigned short (*Bs)[512] = (unsigned short(*)[512])(Sh + 8192);

    const int tid  = threadIdx.x;
    const int lane = tid & 63;
    const int wave = tid >> 6;

    // XCD-aware swizzle (N-split grid.x==4 case = GEMM1)
    int bx, by;
    if (gridDim.x == 4) {
        int id = blockIdx.y * 4 + blockIdx.x;
        int full = (gridDim.y & ~7) * 4;
        if (id < full) {
            bx = (id >> 3) & 3;
            by = (id >> 5) * 8 + (id & 7);
        } else {
            int t = id - full;
            by = (gridDim.y & ~7) + (t >> 2);
            bx = t & 3;
        }
    } else {
        bx = blockIdx.x; by = blockIdx.y;
    }
    const int bM = by * BM;
    const int bN = bx * BN;
    const int wm = (wave >> 1) * 64;
    const int wn = (wave & 1) * 64;
    const int q    = lane >> 4;
    const int mrow = lane & 15;

    // contiguous staging: wave copies 4KB of the 16KB tile-step block (A and B)
    const unsigned short* as_ = A  + (((size_t)by * NKT) << 13) + (wave << 11) + (lane << 3);
    const unsigned short* bs_ = Bt + (((size_t)bx * NKT) << 13) + (wave << 11) + (lane << 3);

    floatx4 acc[4][4];
#pragma unroll
    for (int i = 0; i < 4; i++)
#pragma unroll
        for (int j = 0; j < 4; j++) acc[i][j] = (floatx4)(0.0f);

    for (int t = 0; t < NKT; ++t) {
#pragma unroll
        for (int c = 0; c < 4; c++) {
            gload_lds16(as_ + (c << 9), Sh + (wave << 11) + (c << 9));
            gload_lds16(bs_ + (c << 9), Sh + 8192 + (wave << 11) + (c << 9));
        }
        __syncthreads();

#pragma unroll
        for (int s = 0; s < 2; s++) {
            bf16x8 af[4], bfv[4];
#pragma unroll
            for (int mi = 0; mi < 4; mi++)
                af[mi] = *(const bf16x8*)&As[s * 8 + (wave >> 1) * 4 + mi][lane * 8];
#pragma unroll
            for (int ni = 0; ni < 4; ni++)
                bfv[ni] = *(const bf16x8*)&Bs[s * 8 + (wave & 1) * 4 + ni][lane * 8];
#pragma unroll
            for (int mi = 0; mi < 4; mi++)
#pragma unroll
                for (int ni = 0; ni < 4; ni++)
                    acc[mi][ni] = __builtin_amdgcn_mfma_f32_16x16x32_bf16(
                        af[mi], bfv[ni], acc[mi][ni], 0, 0, 0);
        }
        __syncthreads();
        as_ += 8192; bs_ += 8192;
    }

    // ---- epilogue: per-wave LDS repack -> 16B/lane coalesced stores ----
    unsigned short* lbuf = Sh + wave * 2048;
    float bv[4];
#pragma unroll
    for (int ni = 0; ni < 4; ni++) bv[ni] = bias[bN + wn + ni * 16 + mrow];

#pragma unroll
    for (int p = 0; p < 2; p++) {
#pragma unroll
        for (int mh = 0; mh < 2; mh++) {
            int mi = 2 * p + mh;
#pragma unroll
            for (int ni = 0; ni < 4; ni++)
#pragma unroll
                for (int r = 0; r < 4; r++)
                    lbuf[(mh * 16 + q * 4 + r) * 64 + ni * 16 + mrow] =
                        f2bf(acc[mi][ni][r] + bv[ni]);
        }
#pragma unroll
        for (int i = 0; i < 4; i++) {
            int prow = i * 8 + (lane >> 3);
            int pcol = (lane & 7) * 8;
            int grow = bM + wm + p * 32 + prow;
            if (grow < M)
                *(ushortx8*)(C + (size_t)grow * N + bN + wn + pcol) =
                    *(const ushortx8*)&lbuf[prow * 64 + pcol];
        }
    }
}

// ---------- propagate step: one wave per dst node, slot-array edges ----------
template <int VEC> struct VecT;
template <> struct VecT<8> { typedef ushortx8 type; };
template <> struct VecT<2> { typedef ushortx2 type; };

template <int VEC, bool ADD_SELF, bool RELU, bool OUT_F32, bool OUT_STAGED = false>
__global__ __launch_bounds__(256) void prop_step_kernel(
    const unsigned short* __restrict__ cur,  // bf16 [Nn, F] linear
    void* __restrict__ outp,                 // bf16/fp32 linear, or staged bf16
    const int* __restrict__ cnt,             // per-mask degree (pre-offset)
    const int* __restrict__ list,            // per-mask src slots (pre-offset)
    int Nn)
{
    typedef typename VecT<VEC>::type VT;
    const int w = blockIdx.x * 4 + (threadIdx.x >> 6);
    if (w >= Nn) return;
    const int lane = threadIdx.x & 63;
    const int F = VEC * 64;
    const size_t off = (size_t)w * F + lane * VEC;

    int deg = cnt[w];
    if (deg > CAP) deg = CAP;
    const int* lp = list + (size_t)w * CAP;

    float acc[VEC];
    if (ADD_SELF) {
        VT v = *(const VT*)(cur + off);
#pragma unroll
        for (int i = 0; i < VEC; i++) acc[i] = bf2f(v[i]);
    } else {
#pragma unroll
        for (int i = 0; i < VEC; i++) acc[i] = 0.0f;
    }

    // independent iterations: src loads + row gathers pipeline freely
    for (int j = 0; j < deg; ++j) {
        int s = lp[j];
        VT v = *(const VT*)(cur + (size_t)s * F + lane * VEC);
#pragma unroll
        for (int i = 0; i < VEC; i++) acc[i] += bf2f(v[i]);
    }

#pragma unroll
    for (int i = 0; i < VEC; i++)
        if (RELU && acc[i] < 0.0f) acc[i] = 0.0f;

    if (OUT_F32) {
        float* out = (float*)outp;
        float2 o2;
#pragma unroll
        for (int i = 0; i < VEC; i += 2) {
            o2.x = acc[i]; o2.y = acc[i + 1];
            *(float2*)(out + off + i) = o2;
        }
    } else {
        VT o;
#pragma unroll
        for (int i = 0; i < VEC; i++) o[i] = f2bf(acc[i]);
        if (OUT_STAGED && VEC == 8) {
            *(VT*)((unsigned short*)outp + staged_chunk(w, lane)) = o;
        } else {
            *(VT*)((unsigned short*)outp + off) = o;
        }
    }
}

// ---------- launch ----------
extern "C" void kernel_launch(void* const* d_in, const int* in_sizes, int n_in,
                              void* d_out, int out_size, void* d_ws, size_t ws_size,
                              hipStream_t stream)
{
    const float* x  = (const float*)d_in[0];       // [Nn, 512] fp32
    const int*   ei = (const int*)d_in[1];         // [2, E] int32
    const int*   em = (const int*)d_in[2];         // [E]
    const float* W1 = (const float*)d_in[5];       // [512,512]
    const float* b1 = (const float*)d_in[6];       // [512]
    const float* W2 = (const float*)d_in[7];       // [512,128]
    const float* b2 = (const float*)d_in[8];       // [128]

    const int FIN = 512, FOUT = 128;
    const int Nn = in_sizes[0] / FIN;   // 60000
    const int E  = in_sizes[2];         // 160000
    const int Mpad = ((Nn + 127) >> 7) << 7;   // 60032

    char* ws = (char*)d_ws;
    size_t off = 0;
    auto alloc = [&](size_t bytes) -> char* {
        char* p = ws + off;
        off += (bytes + 255) & ~(size_t)255;
        return p;
    };
    unsigned short* W1t = (unsigned short*)alloc((size_t)FIN * FIN * 2);   // staged
    unsigned short* W2t = (unsigned short*)alloc((size_t)FIN * FOUT * 2);  // staged
    unsigned short* xb  = (unsigned short*)alloc((size_t)Mpad * FIN * 2);  // staged x; reused as A1 (linear)
    unsigned short* h1  = (unsigned short*)alloc((size_t)Mpad * FIN * 2);  // GEMM1 out (linear) -> B1 staged
    unsigned short* h2  = (unsigned short*)alloc((size_t)Nn * FOUT * 2);
    unsigned short* A2  = (unsigned short*)alloc((size_t)Nn * FOUT * 2);
    int* cnt  = (int*)alloc((size_t)2 * Nn * 4);            // [2][Nn] degrees
    int* list = (int*)alloc((size_t)2 * Nn * CAP * 4);      // [2][Nn][CAP] src ids
    unsigned short* A1 = xb;
    (void)ws_size; (void)n_in; (void)out_size;

    // 1) convert x -> staged; transpose+convert weights -> staged
    {
        int nchunk = Nn * (FIN / 8);
        cvt_f32_bf16_staged_kernel<<<(nchunk + 255) / 256, 256, 0, stream>>>(x, xb, nchunk);
    }
    transpose_cvt_staged_kernel<<<(FIN * FIN + 255) / 256, 256, 0, stream>>>(W1, W1t, FIN, FIN);
    transpose_cvt_staged_kernel<<<(FIN * FOUT + 255) / 256, 256, 0, stream>>>(W2, W2t, FIN, FOUT);

    // 2) per-(mask,dst) slot arrays
    zero_cnt_kernel<<<(2 * Nn + 255) / 256, 256, 0, stream>>>(cnt, 2 * Nn);
    build_slots_kernel<<<(E + 255) / 256, 256, 0, stream>>>(ei, em, E, Nn, cnt, list);

    // 3) h1 = x @ W1 + b1   (staged A/B)
    {
        dim3 grid(FIN / BN, Mpad / BM);
        gemm_bt_bias<<<grid, 256, 0, stream>>>(xb, W1t, b1, h1, Nn, FIN, FIN);
    }

    // 4) P1: A1 = S0(h1) (linear);  B1 = relu(A1 + S1(A1)) -> STAGED into h1
    {
        int grid = (Nn + 3) / 4;
        prop_step_kernel<8, false, false, false, false><<<grid, 256, 0, stream>>>(
            h1, A1, cnt, list, Nn);
        prop_step_kernel<8, true,  true,  false, true ><<<grid, 256, 0, stream>>>(
            A1, h1, cnt + Nn, list + (size_t)Nn * CAP, Nn);
    }

    // 5) h2 = B1 @ W2 + b2   (staged A/B)
    {
        dim3 grid(FOUT / BN, Mpad / BM);
        gemm_bt_bias<<<grid, 256, 0, stream>>>(h1, W2t, b2, h2, Nn, FOUT, FIN);
    }

    // 6) P2: A2 = S0(h2);  out = A2 + S1(A2)  (fp32)
    {
        int grid = (Nn + 3) / 4;
        prop_step_kernel<2, false, false, false><<<grid, 256, 0, stream>>>(
            h2, A2, cnt, list, Nn);
        prop_step_kernel<2, true,  false, true ><<<grid, 256, 0, stream>>>(
            A2, d_out, cnt + Nn, list + (size_t)Nn * CAP, Nn);
    }
}

// Round 10
// 385.429 us; speedup vs baseline: 1.0647x; 1.0647x over previous
//
#include <hip/hip_runtime.h>

// ---------- types ----------
typedef __bf16 bf16x8 __attribute__((ext_vector_type(8)));
typedef float  floatx4 __attribute__((ext_vector_type(4)));
typedef unsigned short ushortx8 __attribute__((ext_vector_type(8)));
typedef unsigned short ushortx4 __attribute__((ext_vector_type(4)));
typedef unsigned short ushortx2 __attribute__((ext_vector_type(2)));

__device__ __forceinline__ float bf2f(unsigned short u) {
    return __uint_as_float(((unsigned)u) << 16);
}
__device__ __forceinline__ unsigned short f2bf(float f) {
    unsigned u = __float_as_uint(f);
    return (unsigned short)((u + 0x7FFFu + ((u >> 16) & 1u)) >> 16);
}

// async global->LDS, 16B per lane; lds dest = wave-uniform base + lane*16.
// NOTE (r6): NEVER use the builtin's imm-offset field (NaN — offset applies to
// the LDS side). All offsets in the global ADDRESS; offset arg always 0.
__device__ __forceinline__ void gload_lds16(const unsigned short* g, unsigned short* l) {
    __builtin_amdgcn_global_load_lds(
        (const __attribute__((address_space(1))) void*)g,
        (__attribute__((address_space(3))) void*)l, 16, 0, 0);
}

// ============================================================================
// STAGED (fragment-order) GLOBAL LAYOUT (r7): A/B pre-packed in the exact
// per-(row-tile,K-step) LDS image so GEMM staging reads are 1KB contiguous.
//   elem = ((tile*8+kti)<<13) + ((s*8+g)<<9) + ((q*16+mrow)<<3) + (k&7)
// ============================================================================
#define NKT 8   // K=512 -> 8 K-steps of 64

__device__ __forceinline__ size_t staged_chunk(int r, int c /*k>>3*/) {
    int tile = r >> 7, rt = r & 127;
    int g = rt >> 4, mrow = rt & 15;
    int kti = c >> 3, c7 = c & 7;
    int s = c7 >> 2, q = c7 & 3;
    return (((size_t)tile * NKT + kti) << 13) + ((size_t)(s * 8 + g) << 9)
         + ((size_t)((q << 4) | mrow) << 3);
}

// ============================================================================
// LAUNCH-COUNT REDUCTION (r10): accounting across r3/r4/r5 puts kernels at
// ~265us vs ~395 measured — the ~130us gap matches ~10us/launch x 11 in-order
// launches (rocprof.md: launch overhead dominates short memory-bound kernels).
// Fuse the 4 independent prep kernels {cvt, trW1, trW2, init_head} into ONE
// grid-stitched kernel (build stays separate: must observe init). 11 -> 8.
// Slot arrays (r9) REVERTED: -18us regression (metadata cache footprint).
// ============================================================================
__global__ __launch_bounds__(256) void prep_kernel(
    const float* __restrict__ x,  unsigned short* __restrict__ xb,  int nchunk, int bc,
    const float* __restrict__ W1, unsigned short* __restrict__ W1t, int bw1,
    const float* __restrict__ W2, unsigned short* __restrict__ W2t, int bw2,
    int* __restrict__ head, int nhead, int FIN, int FOUT)
{
    const int bid = blockIdx.x, tid = threadIdx.x;
    if (bid < bc) {
        // ---- cvt: x fp32 [Nn,512] -> staged bf16 (one thread per 8-chunk) ----
        int i = bid * 256 + tid;
        if (i < nchunk) {
            int r = i >> 6, c = i & 63;
            float4 v0 = ((const float4*)x)[i * 2];
            float4 v1 = ((const float4*)x)[i * 2 + 1];
            ushortx8 o;
            o[0] = f2bf(v0.x); o[1] = f2bf(v0.y); o[2] = f2bf(v0.z); o[3] = f2bf(v0.w);
            o[4] = f2bf(v1.x); o[5] = f2bf(v1.y); o[6] = f2bf(v1.z); o[7] = f2bf(v1.w);
            *(ushortx8*)(xb + staged_chunk(r, c)) = o;
        }
    } else if (bid < bc + bw1) {
        // ---- W1 [FIN,FIN] fp32 -> staged bf16 (rows = N-dim) ----
        int idx = (bid - bc) * 256 + tid;
        if (idx < FIN * FIN) {
            int k = idx / FIN, n = idx - k * FIN;
            W1t[staged_chunk(n, k >> 3) + (k & 7)] = f2bf(W1[idx]);
        }
    } else if (bid < bc + bw1 + bw2) {
        // ---- W2 [FIN,FOUT] fp32 -> staged bf16 ----
        int idx = (bid - bc - bw1) * 256 + tid;
        if (idx < FIN * FOUT) {
            int k = idx / FOUT, n = idx - k * FOUT;
            W2t[staged_chunk(n, k >> 3) + (k & 7)] = f2bf(W2[idx]);
        }
    } else {
        // ---- init_head ----
        int i = (bid - bc - bw1 - bw2) * 256 + tid;
        if (i < nhead) head[i] = -1;
    }
}

// two lists per dst: head[mask*Nn + dst] — halves traversal length per step
__global__ void build_list_kernel(const int* __restrict__ ei, const int* __restrict__ em,
                                  int E, int Nn,
                                  int* __restrict__ head, int* __restrict__ nxt) {
    int e = blockIdx.x * blockDim.x + threadIdx.x;
    if (e >= E) return;
    int d = ei[E + e];
    int m = em[e];
    nxt[e] = atomicExch(&head[m * Nn + d], e);
}

// ---------- GEMM: C[M,N] = A@B + bias; A,Bt in STAGED layout; C linear ------
#define BM 128
#define BN 128

__global__ __launch_bounds__(256, 4) void gemm_bt_bias(
    const unsigned short* __restrict__ A,    // staged [tiles][NKT][16KB]
    const unsigned short* __restrict__ Bt,   // staged
    const float* __restrict__ bias,          // N (fp32)
    unsigned short* __restrict__ C,          // M x N  (bf16 bits), linear
    int M, int N, int K)
{
    __shared__ unsigned short Sh[16384];     // 32 KB: As[16][512] + Bs[16][512]
    unsigned short (*As)[512] = (unsigned short(*)[512])Sh;
    unsigned short (*Bs)[512] = (unsigned short(*)[512])(Sh + 8192);

    const int tid  = threadIdx.x;
    const int lane = tid & 63;
    const int wave = tid >> 6;

    // XCD-aware swizzle (N-split grid.x==4 case = GEMM1)
    int bx, by;
    if (gridDim.x == 4) {
        int id = blockIdx.y * 4 + blockIdx.x;
        int full = (gridDim.y & ~7) * 4;
        if (id < full) {
            bx = (id >> 3) & 3;
            by = (id >> 5) * 8 + (id & 7);
        } else {
            int t = id - full;
            by = (gridDim.y & ~7) + (t >> 2);
            bx = t & 3;
        }
    } else {
        bx = blockIdx.x; by = blockIdx.y;
    }
    const int bM = by * BM;
    const int bN = bx * BN;
    const int wm = (wave >> 1) * 64;
    const int wn = (wave & 1) * 64;
    const int q    = lane >> 4;
    const int mrow = lane & 15;

    // contiguous staging: wave copies 4KB of the 16KB tile-step block (A and B)
    const unsigned short* as_ = A  + (((size_t)by * NKT) << 13) + (wave << 11) + (lane << 3);
    const unsigned short* bs_ = Bt + (((size_t)bx * NKT) << 13) + (wave << 11) + (lane << 3);

    floatx4 acc[4][4];
#pragma unroll
    for (int i = 0; i < 4; i++)
#pragma unroll
        for (int j = 0; j < 4; j++) acc[i][j] = (floatx4)(0.0f);

    for (int t = 0; t < NKT; ++t) {
#pragma unroll
        for (int c = 0; c < 4; c++) {
            gload_lds16(as_ + (c << 9), Sh + (wave << 11) + (c << 9));
            gload_lds16(bs_ + (c << 9), Sh + 8192 + (wave << 11) + (c << 9));
        }
        __syncthreads();

#pragma unroll
        for (int s = 0; s < 2; s++) {
            bf16x8 af[4], bfv[4];
#pragma unroll
            for (int mi = 0; mi < 4; mi++)
                af[mi] = *(const bf16x8*)&As[s * 8 + (wave >> 1) * 4 + mi][lane * 8];
#pragma unroll
            for (int ni = 0; ni < 4; ni++)
                bfv[ni] = *(const bf16x8*)&Bs[s * 8 + (wave & 1) * 4 + ni][lane * 8];
#pragma unroll
            for (int mi = 0; mi < 4; mi++)
#pragma unroll
                for (int ni = 0; ni < 4; ni++)
                    acc[mi][ni] = __builtin_amdgcn_mfma_f32_16x16x32_bf16(
                        af[mi], bfv[ni], acc[mi][ni], 0, 0, 0);
        }
        __syncthreads();
        as_ += 8192; bs_ += 8192;
    }

    // ---- epilogue: per-wave LDS repack -> 16B/lane coalesced stores ----
    unsigned short* lbuf = Sh + wave * 2048;
    float bv[4];
#pragma unroll
    for (int ni = 0; ni < 4; ni++) bv[ni] = bias[bN + wn + ni * 16 + mrow];

#pragma unroll
    for (int p = 0; p < 2; p++) {
#pragma unroll
        for (int mh = 0; mh < 2; mh++) {
            int mi = 2 * p + mh;
#pragma unroll
            for (int ni = 0; ni < 4; ni++)
#pragma unroll
                for (int r = 0; r < 4; r++)
                    lbuf[(mh * 16 + q * 4 + r) * 64 + ni * 16 + mrow] =
                        f2bf(acc[mi][ni][r] + bv[ni]);
        }
#pragma unroll
        for (int i = 0; i < 4; i++) {
            int prow = i * 8 + (lane >> 3);
            int pcol = (lane & 7) * 8;
            int grow = bM + wm + p * 32 + prow;
            if (grow < M)
                *(ushortx8*)(C + (size_t)grow * N + bN + wn + pcol) =
                    *(const ushortx8*)&lbuf[prow * 64 + pcol];
        }
    }
}

// ---------- propagate step: one wave per dst node, linked-list edges ----------
template <int VEC> struct VecT;
template <> struct VecT<8> { typedef ushortx8 type; };
template <> struct VecT<2> { typedef ushortx2 type; };

template <int VEC, bool ADD_SELF, bool RELU, bool OUT_F32, bool OUT_STAGED = false>
__global__ __launch_bounds__(256, 8) void prop_step_kernel(
    const unsigned short* __restrict__ cur,  // bf16 [Nn, F] linear
    void* __restrict__ outp,                 // bf16/fp32 linear, or staged bf16
    const int* __restrict__ head,            // per-mask list heads (pre-offset)
    const int* __restrict__ nxt,
    const int* __restrict__ esrc,
    int Nn)
{
    typedef typename VecT<VEC>::type VT;
    const int w = blockIdx.x * 4 + (threadIdx.x >> 6);
    if (w >= Nn) return;
    const int lane = threadIdx.x & 63;
    const int F = VEC * 64;
    const size_t off = (size_t)w * F + lane * VEC;

    float acc[VEC];
    if (ADD_SELF) {
        VT v = *(const VT*)(cur + off);
#pragma unroll
        for (int i = 0; i < VEC; i++) acc[i] = bf2f(v[i]);
    } else {
#pragma unroll
        for (int i = 0; i < VEC; i++) acc[i] = 0.0f;
    }

    for (int e = head[w]; e >= 0; e = nxt[e]) {
        int s = esrc[e];
        VT v = *(const VT*)(cur + (size_t)s * F + lane * VEC);
#pragma unroll
        for (int i = 0; i < VEC; i++) acc[i] += bf2f(v[i]);
    }

#pragma unroll
    for (int i = 0; i < VEC; i++)
        if (RELU && acc[i] < 0.0f) acc[i] = 0.0f;

    if (OUT_F32) {
        float* out = (float*)outp;
        float2 o2;
#pragma unroll
        for (int i = 0; i < VEC; i += 2) {
            o2.x = acc[i]; o2.y = acc[i + 1];
            *(float2*)(out + off + i) = o2;
        }
    } else {
        VT o;
#pragma unroll
        for (int i = 0; i < VEC; i++) o[i] = f2bf(acc[i]);
        if (OUT_STAGED && VEC == 8) {
            *(VT*)((unsigned short*)outp + staged_chunk(w, lane)) = o;
        } else {
            *(VT*)((unsigned short*)outp + off) = o;
        }
    }
}

// ---------- launch ----------
extern "C" void kernel_launch(void* const* d_in, const int* in_sizes, int n_in,
                              void* d_out, int out_size, void* d_ws, size_t ws_size,
                              hipStream_t stream)
{
    const float* x  = (const float*)d_in[0];       // [Nn, 512] fp32
    const int*   ei = (const int*)d_in[1];         // [2, E] int32
    const int*   em = (const int*)d_in[2];         // [E]
    const float* W1 = (const float*)d_in[5];       // [512,512]
    const float* b1 = (const float*)d_in[6];       // [512]
    const float* W2 = (const float*)d_in[7];       // [512,128]
    const float* b2 = (const float*)d_in[8];       // [128]

    const int FIN = 512, FOUT = 128;
    const int Nn = in_sizes[0] / FIN;   // 60000
    const int E  = in_sizes[2];         // 160000
    const int Mpad = ((Nn + 127) >> 7) << 7;   // 60032

    char* ws = (char*)d_ws;
    size_t off = 0;
    auto alloc = [&](size_t bytes) -> char* {
        char* p = ws + off;
        off += (bytes + 255) & ~(size_t)255;
        return p;
    };
    unsigned short* W1t = (unsigned short*)alloc((size_t)FIN * FIN * 2);   // staged
    unsigned short* W2t = (unsigned short*)alloc((size_t)FIN * FOUT * 2);  // staged
    unsigned short* xb  = (unsigned short*)alloc((size_t)Mpad * FIN * 2);  // staged x; reused as A1 (linear)
    unsigned short* h1  = (unsigned short*)alloc((size_t)Mpad * FIN * 2);  // GEMM1 out (linear) -> B1 staged
    unsigned short* h2  = (unsigned short*)alloc((size_t)Nn * FOUT * 2);
    unsigned short* A2  = (unsigned short*)alloc((size_t)Nn * FOUT * 2);
    int* head = (int*)alloc((size_t)2 * Nn * 4);   // [2][Nn]
    int* nxt  = (int*)alloc((size_t)E * 4);
    unsigned short* A1 = xb;
    (void)ws_size; (void)n_in; (void)out_size;

    // 1) fused prep: cvt x -> staged, W1/W2 -> staged, init head   (1 launch)
    {
        int nchunk = Nn * (FIN / 8);
        int bc  = (nchunk + 255) / 256;
        int bw1 = (FIN * FIN + 255) / 256;
        int bw2 = (FIN * FOUT + 255) / 256;
        int bh  = (2 * Nn + 255) / 256;
        prep_kernel<<<bc + bw1 + bw2 + bh, 256, 0, stream>>>(
            x, xb, nchunk, bc, W1, W1t, bw1, W2, W2t, bw2, head, 2 * Nn, FIN, FOUT);
    }

    // 2) per-(mask,dst) linked lists (after init)
    build_list_kernel<<<(E + 255) / 256, 256, 0, stream>>>(ei, em, E, Nn, head, nxt);

    // 3) h1 = x @ W1 + b1   (staged A/B)
    {
        dim3 grid(FIN / BN, Mpad / BM);
        gemm_bt_bias<<<grid, 256, 0, stream>>>(xb, W1t, b1, h1, Nn, FIN, FIN);
    }

    // 4) P1: A1 = S0(h1) (linear);  B1 = relu(A1 + S1(A1)) -> STAGED into h1
    {
        int grid = (Nn + 3) / 4;
        prop_step_kernel<8, false, false, false, false><<<grid, 256, 0, stream>>>(
            h1, A1, head, nxt, ei, Nn);
        prop_step_kernel<8, true,  true,  false, true ><<<grid, 256, 0, stream>>>(
            A1, h1, head + Nn, nxt, ei, Nn);
    }

    // 5) h2 = B1 @ W2 + b2   (staged A/B)
    {
        dim3 grid(FOUT / BN, Mpad / BM);
        gemm_bt_bias<<<grid, 256, 0, stream>>>(h1, W2t, b2, h2, Nn, FOUT, FIN);
    }

    // 6) P2: A2 = S0(h2);  out = A2 + S1(A2)  (fp32)
    {
        int grid = (Nn + 3) / 4;
        prop_step_kernel<2, false, false, false><<<grid, 256, 0, stream>>>(
            h2, A2, head, nxt, ei, Nn);
        prop_step_kernel<2, true,  false, true ><<<grid, 256, 0, stream>>>(
            A2, d_out, head + Nn, nxt, ei, Nn);
    }
}